// Round 7
// baseline (5693.669 us; speedup 1.0000x reference)
//
#include <hip/hip_runtime.h>
#include <hip/hip_fp16.h>

#define NN 100000
#define NE 1600000
#define CHUNK 1024
#define NCHUNK ((NN + CHUNK - 1) / CHUNK)

union H2x4 { uint4 u; __half2 h[4]; };

// ---------------- preprocessing ----------------

__global__ void count_kernel(const int* __restrict__ dst, int* __restrict__ cnt) {
    int e = blockIdx.x * blockDim.x + threadIdx.x;
    if (e < NE) atomicAdd(&cnt[dst[e]], 1);
}

// dis[i] = rsqrt(deg_i+1);  xs4 = dis-prescaled x rows, padded to float4
__global__ void dis_xs_kernel(const int* __restrict__ cnt, const float* __restrict__ x,
                              float* __restrict__ dis, float4* __restrict__ xs4) {
    int i = blockIdx.x * blockDim.x + threadIdx.x;
    if (i >= NN) return;
    float d = rsqrtf((float)(cnt[i] + 1));
    dis[i] = d;
    xs4[i] = make_float4(d * x[i * 3 + 0], d * x[i * 3 + 1], d * x[i * 3 + 2], 0.f);
}

// hierarchical exclusive scan of (cnt[i]+1)  [self-loop included in CSR]
__global__ __launch_bounds__(256) void scan1_kernel(const int* __restrict__ cnt,
                                                    int* __restrict__ row_ptr,
                                                    int* __restrict__ sums) {
    __shared__ int sdata[256];
    const int b = blockIdx.x, t = threadIdx.x;
    const int base = b * CHUNK + t * 4;
    int v0 = (base + 0 < NN) ? cnt[base + 0] + 1 : 0;
    int v1 = (base + 1 < NN) ? cnt[base + 1] + 1 : 0;
    int v2 = (base + 2 < NN) ? cnt[base + 2] + 1 : 0;
    int v3 = (base + 3 < NN) ? cnt[base + 3] + 1 : 0;
    const int s = v0 + v1 + v2 + v3;
    sdata[t] = s;
    __syncthreads();
    for (int off = 1; off < 256; off <<= 1) {
        int xv = (t >= off) ? sdata[t - off] : 0;
        __syncthreads();
        sdata[t] += xv;
        __syncthreads();
    }
    const int excl = sdata[t] - s;
    if (base + 0 < NN) row_ptr[base + 0] = excl;
    if (base + 1 < NN) row_ptr[base + 1] = excl + v0;
    if (base + 2 < NN) row_ptr[base + 2] = excl + v0 + v1;
    if (base + 3 < NN) row_ptr[base + 3] = excl + v0 + v1 + v2;
    if (t == 255) sums[b] = sdata[255];
}

__global__ __launch_bounds__(128) void scan2_kernel(int* __restrict__ sums,
                                                    int* __restrict__ row_ptr) {
    __shared__ int sd[128];
    const int t = threadIdx.x;
    const int v = (t < NCHUNK) ? sums[t] : 0;
    sd[t] = v;
    __syncthreads();
    for (int off = 1; off < 128; off <<= 1) {
        int xv = (t >= off) ? sd[t - off] : 0;
        __syncthreads();
        sd[t] += xv;
        __syncthreads();
    }
    if (t < NCHUNK) sums[t] = sd[t] - v;
    if (t == 127) row_ptr[NN] = sd[127];
}

__global__ void scan3_kernel(int* __restrict__ row_ptr, const int* __restrict__ sums) {
    int i = blockIdx.x * blockDim.x + threadIdx.x;
    if (i < NN) row_ptr[i] += sums[i >> 10];
}

// CSR fill: col only (1 edge/thread: max TLP for the atomic->store chain)
__global__ void fill_kernel(const int* __restrict__ src, const int* __restrict__ dst,
                            const int* __restrict__ row_ptr, int* __restrict__ fil,
                            int* __restrict__ col) {
    int e = blockIdx.x * blockDim.x + threadIdx.x;
    if (e >= NE) return;
    int d = dst[e];
    int pos = atomicAdd(&fil[d], 1);
    col[row_ptr[d] + pos] = src[e];
}

__global__ void selffill_kernel(const int* __restrict__ row_ptr, const int* __restrict__ cnt,
                                int* __restrict__ col) {
    int i = blockIdx.x * blockDim.x + threadIdx.x;
    if (i >= NN) return;
    col[row_ptr[i] + cnt[i]] = i;  // self edge last in the row
}

// ax = Ahat @ x = dis_i * sum_j xs[j]   (CSR includes self loop)
__global__ void aggx_kernel(const float4* __restrict__ xs4, const int* __restrict__ row_ptr,
                            const int* __restrict__ col, const float* __restrict__ dis,
                            float* __restrict__ ax) {
    int i = blockIdx.x * blockDim.x + threadIdx.x;
    if (i >= NN) return;
    float a0 = 0.f, a1 = 0.f, a2 = 0.f;
    const int s = row_ptr[i], e = row_ptr[i + 1];
    int p = s;
    for (; p + 2 <= e; p += 2) {
        const float4 v0 = xs4[col[p]];
        const float4 v1 = xs4[col[p + 1]];
        a0 += v0.x + v1.x; a1 += v0.y + v1.y; a2 += v0.z + v1.z;
    }
    if (p < e) {
        const float4 v = xs4[col[p]];
        a0 += v.x; a1 += v.y; a2 += v.z;
    }
    const float d = dis[i];
    ax[i * 3 + 0] = d * a0; ax[i * 3 + 1] = d * a1; ax[i * 3 + 2] = d * a2;
}

// t16 = fp16(dis * relu(ax @ Wp + bp));  xr = ax @ Wr[64:67,:] + br
__global__ void proj_kernel(const float* __restrict__ ax,
                            const float* __restrict__ Wp, const float* __restrict__ bp,
                            const float* __restrict__ Wr, const float* __restrict__ br,
                            const float* __restrict__ dis,
                            __half* __restrict__ t16, float* __restrict__ xr) {
    int g = blockIdx.x * blockDim.x + threadIdx.x;
    if (g >= NN * 64) return;
    int i = g >> 6, c = g & 63;
    float a0 = ax[i * 3 + 0], a1 = ax[i * 3 + 1], a2 = ax[i * 3 + 2];
    float tp = fmaxf(a0 * Wp[c] + a1 * Wp[64 + c] + a2 * Wp[128 + c] + bp[c], 0.f);
    t16[g] = __float2half(tp * dis[i]);
    xr[g] = a0 * Wr[64 * 64 + c] + a1 * Wr[65 * 64 + c] + a2 * Wr[66 * 64 + c] + br[c];
}

// ---------------- fused GCN ----------------
// h16 rows fp16, pre-scaled by dis[j]. agg_i = dis_i * sum_{j in row} h16[j].
// Phase 1: 3-stage software pipeline per wave over its 16 rows:
//   colv(rr+2) -> gathers(rr+1) -> reduce(rr)
// so 8 gathers + 4 colv loads stay in flight across every reduce (smooths the
// per-XCD L2-miss queue; the fabric pull of h16 is the compulsory floor).
// Gather FMA is packed fp16 (v_pk_fma_f16, mask as half2); first shuffle round
// in fp16, rest fp32 (<=5 fp16 partial-sum roundings -> ~1e-3 added error).
// Phase 2: [64 x IN_W] fp32 @ [IN_W x OUT_W], W from global (L1-resident).

template <int IN_W, int OUT_W, bool RELU, bool HAS_ADD, bool HAS_BIAS, bool W32, bool W16>
__global__ __launch_bounds__(256, 6) void gcn_kernel(
    const __half* __restrict__ h16, const float* __restrict__ Wg,
    const float* __restrict__ bias, const float* __restrict__ addsrc,
    const int* __restrict__ row_ptr, const int* __restrict__ colv,
    const float* __restrict__ dis,
    float* __restrict__ out32, __half* __restrict__ out16) {
    constexpr int TILE_R = 64;
    constexpr int QUADS = IN_W / 8;      // lanes per row (16B = 8 halves each)
    constexpr int SLOTS = 64 / QUADS;    // rows gathered per wave instruction
    constexpr int STR = IN_W + 4;
    __shared__ __align__(16) float aggT[TILE_R][STR];
    __shared__ int rp[TILE_R + 1];
    __shared__ float rdis[TILE_R];

    const int tid = threadIdx.x;
    const int tile0 = blockIdx.x * TILE_R;

    if (tid <= TILE_R) rp[tid] = row_ptr[min(tile0 + tid, NN)];
    if (tid < TILE_R) {
        const int i = tile0 + tid;
        rdis[tid] = (i < NN) ? dis[i] : 0.f;
    }
    __syncthreads();

    const int wave = tid >> 6;
    const int lane = tid & 63;
    const int fq = lane & (QUADS - 1);
    const int slot = lane / QUADS;
    const int rbase = wave << 4;
    const size_t fqo = (size_t)(fq << 3);

    auto loadC = [&](int* cb, int rl) {
        const int s = rp[rl], e = rp[rl + 1];
        const int last = e - 1;
        const int p0 = s + slot;
        cb[0] = colv[min(p0, last)];
        cb[1] = colv[min(p0 + SLOTS, last)];
        cb[2] = colv[min(p0 + 2 * SLOTS, last)];
        cb[3] = colv[min(p0 + 3 * SLOTS, last)];
    };
    auto loadG = [&](uint4* gb, const int* cb) {
#pragma unroll
        for (int k = 0; k < 4; ++k)
            gb[k] = *(const uint4*)(h16 + (size_t)cb[k] * IN_W + fqo);
    };

    int cbuf[2][4];
    uint4 gbuf[2][4];
    loadC(cbuf[0], rbase);
    loadG(gbuf[0], cbuf[0]);
    loadC(cbuf[1], rbase + 1);

    const __half2 ONE2 = __float2half2_rn(1.0f);
    const __half2 ZERO2 = __float2half2_rn(0.0f);

    for (int rr = 0; rr < 16; ++rr) {
        const int cu = rr & 1, nx = cu ^ 1;
        if (rr + 1 < 16) loadG(gbuf[nx], cbuf[nx]);          // gathers for next row
        if (rr + 2 < 16) loadC(cbuf[cu], rbase + rr + 2);    // colv for row after

        // ---- reduce row rr from gbuf[cu] ----
        const int rl = rbase + rr;
        const int s = rp[rl], e = rp[rl + 1];
        const int p0 = s + slot;
        __half2 acc[4] = {ZERO2, ZERO2, ZERO2, ZERO2};
        H2x4 hh;
#pragma unroll
        for (int k = 0; k < 4; ++k) {
            const __half2 mk = (p0 + k * SLOTS < e) ? ONE2 : ZERO2;
            hh.u = gbuf[cu][k];
#pragma unroll
            for (int t = 0; t < 4; ++t) acc[t] = __hfma2(hh.h[t], mk, acc[t]);
        }
        if (e - s > 4 * SLOTS) {  // rare tail (deg > 4*SLOTS)
            for (int p = p0 + 4 * SLOTS; p < e; p += SLOTS) {
                const int j = colv[p];
                hh.u = *(const uint4*)(h16 + (size_t)j * IN_W + fqo);
#pragma unroll
                for (int t = 0; t < 4; ++t) acc[t] = __hadd2(acc[t], hh.h[t]);
            }
        }
        // tree round 1 (fp16, xor = QUADS)
#pragma unroll
        for (int t = 0; t < 4; ++t) {
            int v = __shfl_xor(*reinterpret_cast<const int*>(&acc[t]), QUADS, 64);
            acc[t] = __hadd2(acc[t], *reinterpret_cast<const __half2*>(&v));
        }
        float f[8];
#pragma unroll
        for (int t = 0; t < 4; ++t) {
            const float2 p2 = __half22float2(acc[t]);
            f[2 * t] = p2.x; f[2 * t + 1] = p2.y;
        }
#pragma unroll
        for (int m = 2 * QUADS; m < 64; m <<= 1) {
#pragma unroll
            for (int t = 0; t < 8; ++t) f[t] += __shfl_xor(f[t], m, 64);
        }
        if (slot == 0) {
            const float d = rdis[rl];
#pragma unroll
            for (int t = 0; t < 8; ++t) f[t] *= d;
            *(float4*)&aggT[rl][(fq << 3)]     = make_float4(f[0], f[1], f[2], f[3]);
            *(float4*)&aggT[rl][(fq << 3) + 4] = make_float4(f[4], f[5], f[6], f[7]);
        }
    }
    __syncthreads();

    // phase 2: [64 x IN_W] fp32 @ [IN_W x OUT_W], W from global (L1-resident)
    constexpr int CPT = (OUT_W >= 4) ? 4 : OUT_W;
    constexpr int TXN = OUT_W / CPT;
    const int tx = tid % TXN;
    const int ty = tid / TXN;
    if (ty < TILE_R / 4) {
        float c[4][CPT];
#pragma unroll
        for (int r = 0; r < 4; ++r)
#pragma unroll
            for (int q = 0; q < CPT; ++q) c[r][q] = 0.f;

#pragma unroll 2
        for (int k4 = 0; k4 < IN_W / 4; ++k4) {
            float4 av[4];
#pragma unroll
            for (int r = 0; r < 4; ++r) av[r] = *(const float4*)&aggT[ty * 4 + r][k4 << 2];
#pragma unroll
            for (int kk = 0; kk < 4; ++kk) {
                float wv[CPT];
                if constexpr (CPT == 4) {
                    const float4 w4 = *(const float4*)(Wg + ((k4 << 2) + kk) * OUT_W + (tx << 2));
                    wv[0] = w4.x; wv[1] = w4.y; wv[2] = w4.z; wv[3] = w4.w;
                } else {
#pragma unroll
                    for (int q = 0; q < CPT; ++q)
                        wv[q] = Wg[((k4 << 2) + kk) * OUT_W + tx * CPT + q];
                }
#pragma unroll
                for (int r = 0; r < 4; ++r) {
                    const float ar = ((const float*)&av[r])[kk];
#pragma unroll
                    for (int q = 0; q < CPT; ++q) c[r][q] += ar * wv[q];
                }
            }
        }
        float bq[CPT];
#pragma unroll
        for (int q = 0; q < CPT; ++q) bq[q] = HAS_BIAS ? bias[tx * CPT + q] : 0.f;
#pragma unroll
        for (int r = 0; r < 4; ++r) {
            const int i = tile0 + ty * 4 + r;
            if (i < NN) {
                float o[CPT];
#pragma unroll
                for (int q = 0; q < CPT; ++q) o[q] = c[r][q] + bq[q];
                if constexpr (HAS_ADD) {
#pragma unroll
                    for (int q = 0; q < CPT; ++q) o[q] += addsrc[i * OUT_W + tx * CPT + q];
                }
                if constexpr (RELU) {
#pragma unroll
                    for (int q = 0; q < CPT; ++q) o[q] = fmaxf(o[q], 0.f);
                }
                if constexpr (W32) {
                    if constexpr (CPT == 4) {
                        *(float4*)(out32 + i * OUT_W + (tx << 2)) =
                            make_float4(o[0], o[1], o[2], o[3]);
                    } else {
#pragma unroll
                        for (int q = 0; q < CPT; ++q) out32[i * OUT_W + tx * CPT + q] = o[q];
                    }
                }
                if constexpr (W16) {
                    const float d = dis[i];
                    if constexpr (CPT == 4) {
                        union { uint2 u; __half2 h[2]; } pk;
                        pk.h[0] = __float22half2_rn(make_float2(o[0] * d, o[1] * d));
                        pk.h[1] = __float22half2_rn(make_float2(o[2] * d, o[3] * d));
                        *(uint2*)(out16 + i * OUT_W + (tx << 2)) = pk.u;
                    } else {
#pragma unroll
                        for (int q = 0; q < CPT; ++q)
                            out16[i * OUT_W + tx * CPT + q] = __float2half(o[q] * d);
                    }
                }
            }
        }
    }
}

// ---------------- driver ----------------

extern "C" void kernel_launch(void* const* d_in, const int* in_sizes, int n_in,
                              void* d_out, int out_size, void* d_ws, size_t ws_size,
                              hipStream_t stream) {
    const float* x   = (const float*)d_in[0];
    const float* Wp  = (const float*)d_in[1];
    const float* bp  = (const float*)d_in[2];
    const float* Wr  = (const float*)d_in[3];
    const float* br  = (const float*)d_in[4];
    const float* W11 = (const float*)d_in[5];
    const float* b11 = (const float*)d_in[6];
    const float* W12 = (const float*)d_in[7];
    const float* b12 = (const float*)d_in[8];
    const float* W21 = (const float*)d_in[9];
    const float* b21 = (const float*)d_in[10];
    const float* W22 = (const float*)d_in[11];
    const float* b22 = (const float*)d_in[12];
    const float* Wh1 = (const float*)d_in[13];
    const float* bh1 = (const float*)d_in[14];
    const float* Wh2 = (const float*)d_in[15];
    const float* bh2 = (const float*)d_in[16];
    const float* Wh3 = (const float*)d_in[17];
    const float* bh3 = (const float*)d_in[18];
    const int* edge  = (const int*)d_in[19];
    const int* srcA = edge;
    const int* dstA = edge + NE;
    float* outp = (float*)d_out;

    char* p = (char*)d_ws;
    auto carve = [&](size_t bytes) {
        char* r = p;
        p += (bytes + 255) & ~(size_t)255;
        return r;
    };
    int*    cnt  = (int*)carve(NN * 4);
    int*    fil  = (int*)carve(NN * 4);
    int*    rptr = (int*)carve((NN + 1) * 4);
    float*  dis  = (float*)carve(NN * 4);
    int*    sums = (int*)carve(128 * 4);
    int*    colv = (int*)carve((size_t)(NE + NN + 256) * 4);
    float4* xs4  = (float4*)carve((size_t)NN * 16);
    float*  ax   = (float*)carve((size_t)NN * 3 * 4);
    float*  xr   = (float*)carve((size_t)NN * 64 * 4);
    float*  bu32 = (float*)carve((size_t)NN * 64 * 4);
    float*  bw32 = (float*)carve((size_t)NN * 64 * 4);
    __half* bt16 = (__half*)carve((size_t)NN * 64 * 2);
    __half* bu16 = (__half*)carve((size_t)NN * 64 * 2);
    __half* bv16 = (__half*)carve((size_t)NN * 64 * 2);
    __half* bw16 = (__half*)carve((size_t)NN * 64 * 2);

    hipMemsetAsync(cnt, 0, NN * 4, stream);
    hipMemsetAsync(fil, 0, NN * 4, stream);
    count_kernel<<<(NE + 255) / 256, 256, 0, stream>>>(dstA, cnt);
    dis_xs_kernel<<<(NN + 255) / 256, 256, 0, stream>>>(cnt, x, dis, xs4);
    scan1_kernel<<<NCHUNK, 256, 0, stream>>>(cnt, rptr, sums);
    scan2_kernel<<<1, 128, 0, stream>>>(sums, rptr);
    scan3_kernel<<<(NN + 255) / 256, 256, 0, stream>>>(rptr, sums);
    fill_kernel<<<(NE + 255) / 256, 256, 0, stream>>>(srcA, dstA, rptr, fil, colv);
    selffill_kernel<<<(NN + 255) / 256, 256, 0, stream>>>(rptr, cnt, colv);
    aggx_kernel<<<(NN + 255) / 256, 256, 0, stream>>>(xs4, rptr, colv, dis, ax);
    proj_kernel<<<(NN * 64 + 255) / 256, 256, 0, stream>>>(ax, Wp, bp, Wr, br, dis, bt16, xr);

    const int GB = (NN + 63) / 64;
    for (int it = 0; it < 5; ++it) {
        gcn_kernel<64, 64, false, true, false, true, true><<<GB, 256, 0, stream>>>(
            bt16, Wr, nullptr, xr, rptr, colv, dis, bu32, bu16);
        gcn_kernel<64, 64, true, false, true, false, true><<<GB, 256, 0, stream>>>(
            bu16, W11, b11, nullptr, rptr, colv, dis, nullptr, bv16);
        gcn_kernel<64, 64, true, true, true, true, true><<<GB, 256, 0, stream>>>(
            bv16, W12, b12, bu32, rptr, colv, dis, bw32, bw16);
        gcn_kernel<64, 64, true, false, true, false, true><<<GB, 256, 0, stream>>>(
            bw16, W21, b21, nullptr, rptr, colv, dis, nullptr, bv16);
        gcn_kernel<64, 64, true, true, true, false, true><<<GB, 256, 0, stream>>>(
            bv16, W22, b22, bw32, rptr, colv, dis, nullptr, bt16);
    }
    gcn_kernel<64, 32, true, false, true, false, true><<<GB, 256, 0, stream>>>(
        bt16, Wh1, bh1, nullptr, rptr, colv, dis, nullptr, bv16);
    gcn_kernel<32, 8, true, false, true, false, true><<<GB, 256, 0, stream>>>(
        bv16, Wh2, bh2, nullptr, rptr, colv, dis, nullptr, bw16);
    gcn_kernel<8, 2, false, false, true, true, false><<<GB, 256, 0, stream>>>(
        bw16, Wh3, bh3, nullptr, rptr, colv, dis, outp, nullptr);
}

// Round 8
// 1679.124 us; speedup vs baseline: 3.3909x; 3.3909x over previous
//
#include <hip/hip_runtime.h>
#include <hip/hip_fp16.h>

#define NN 100000
#define NE 1600000
#define CHUNK 1024
#define NCHUNK ((NN + CHUNK - 1) / CHUNK)

union H2x4 { uint4 u; __half2 h[4]; };

// ---------------- preprocessing ----------------

__global__ void count_kernel(const int* __restrict__ dst, int* __restrict__ cnt) {
    int e = blockIdx.x * blockDim.x + threadIdx.x;
    if (e < NE) atomicAdd(&cnt[dst[e]], 1);
}

// dis[i] = rsqrt(deg_i+1);  xs4 = dis-prescaled x rows, padded to float4
__global__ void dis_xs_kernel(const int* __restrict__ cnt, const float* __restrict__ x,
                              float* __restrict__ dis, float4* __restrict__ xs4) {
    int i = blockIdx.x * blockDim.x + threadIdx.x;
    if (i >= NN) return;
    float d = rsqrtf((float)(cnt[i] + 1));
    dis[i] = d;
    xs4[i] = make_float4(d * x[i * 3 + 0], d * x[i * 3 + 1], d * x[i * 3 + 2], 0.f);
}

// hierarchical exclusive scan of (cnt[i]+1)  [self-loop included in CSR]
__global__ __launch_bounds__(256) void scan1_kernel(const int* __restrict__ cnt,
                                                    int* __restrict__ row_ptr,
                                                    int* __restrict__ sums) {
    __shared__ int sdata[256];
    const int b = blockIdx.x, t = threadIdx.x;
    const int base = b * CHUNK + t * 4;
    int v0 = (base + 0 < NN) ? cnt[base + 0] + 1 : 0;
    int v1 = (base + 1 < NN) ? cnt[base + 1] + 1 : 0;
    int v2 = (base + 2 < NN) ? cnt[base + 2] + 1 : 0;
    int v3 = (base + 3 < NN) ? cnt[base + 3] + 1 : 0;
    const int s = v0 + v1 + v2 + v3;
    sdata[t] = s;
    __syncthreads();
    for (int off = 1; off < 256; off <<= 1) {
        int xv = (t >= off) ? sdata[t - off] : 0;
        __syncthreads();
        sdata[t] += xv;
        __syncthreads();
    }
    const int excl = sdata[t] - s;
    if (base + 0 < NN) row_ptr[base + 0] = excl;
    if (base + 1 < NN) row_ptr[base + 1] = excl + v0;
    if (base + 2 < NN) row_ptr[base + 2] = excl + v0 + v1;
    if (base + 3 < NN) row_ptr[base + 3] = excl + v0 + v1 + v2;
    if (t == 255) sums[b] = sdata[255];
}

__global__ __launch_bounds__(128) void scan2_kernel(int* __restrict__ sums,
                                                    int* __restrict__ row_ptr) {
    __shared__ int sd[128];
    const int t = threadIdx.x;
    const int v = (t < NCHUNK) ? sums[t] : 0;
    sd[t] = v;
    __syncthreads();
    for (int off = 1; off < 128; off <<= 1) {
        int xv = (t >= off) ? sd[t - off] : 0;
        __syncthreads();
        sd[t] += xv;
        __syncthreads();
    }
    if (t < NCHUNK) sums[t] = sd[t] - v;
    if (t == 127) row_ptr[NN] = sd[127];
}

__global__ void scan3_kernel(int* __restrict__ row_ptr, const int* __restrict__ sums) {
    int i = blockIdx.x * blockDim.x + threadIdx.x;
    if (i < NN) row_ptr[i] += sums[i >> 10];
}

// CSR fill: col only (1 edge/thread: max TLP for the atomic->store chain)
__global__ void fill_kernel(const int* __restrict__ src, const int* __restrict__ dst,
                            const int* __restrict__ row_ptr, int* __restrict__ fil,
                            int* __restrict__ col) {
    int e = blockIdx.x * blockDim.x + threadIdx.x;
    if (e >= NE) return;
    int d = dst[e];
    int pos = atomicAdd(&fil[d], 1);
    col[row_ptr[d] + pos] = src[e];
}

__global__ void selffill_kernel(const int* __restrict__ row_ptr, const int* __restrict__ cnt,
                                int* __restrict__ col) {
    int i = blockIdx.x * blockDim.x + threadIdx.x;
    if (i >= NN) return;
    col[row_ptr[i] + cnt[i]] = i;  // self edge last in the row
}

// ax = Ahat @ x = dis_i * sum_j xs[j]   (CSR includes self loop)
__global__ void aggx_kernel(const float4* __restrict__ xs4, const int* __restrict__ row_ptr,
                            const int* __restrict__ col, const float* __restrict__ dis,
                            float* __restrict__ ax) {
    int i = blockIdx.x * blockDim.x + threadIdx.x;
    if (i >= NN) return;
    float a0 = 0.f, a1 = 0.f, a2 = 0.f;
    const int s = row_ptr[i], e = row_ptr[i + 1];
    int p = s;
    for (; p + 2 <= e; p += 2) {
        const float4 v0 = xs4[col[p]];
        const float4 v1 = xs4[col[p + 1]];
        a0 += v0.x + v1.x; a1 += v0.y + v1.y; a2 += v0.z + v1.z;
    }
    if (p < e) {
        const float4 v = xs4[col[p]];
        a0 += v.x; a1 += v.y; a2 += v.z;
    }
    const float d = dis[i];
    ax[i * 3 + 0] = d * a0; ax[i * 3 + 1] = d * a1; ax[i * 3 + 2] = d * a2;
}

// t16 = fp16(dis * relu(ax @ Wp + bp));  xr = ax @ Wr[64:67,:] + br
__global__ void proj_kernel(const float* __restrict__ ax,
                            const float* __restrict__ Wp, const float* __restrict__ bp,
                            const float* __restrict__ Wr, const float* __restrict__ br,
                            const float* __restrict__ dis,
                            __half* __restrict__ t16, float* __restrict__ xr) {
    int g = blockIdx.x * blockDim.x + threadIdx.x;
    if (g >= NN * 64) return;
    int i = g >> 6, c = g & 63;
    float a0 = ax[i * 3 + 0], a1 = ax[i * 3 + 1], a2 = ax[i * 3 + 2];
    float tp = fmaxf(a0 * Wp[c] + a1 * Wp[64 + c] + a2 * Wp[128 + c] + bp[c], 0.f);
    t16[g] = __float2half(tp * dis[i]);
    xr[g] = a0 * Wr[64 * 64 + c] + a1 * Wr[65 * 64 + c] + a2 * Wr[66 * 64 + c] + br[c];
}

// ---------------- fused GCN ----------------
// h16 rows fp16, pre-scaled by dis[j]. agg_i = dis_i * sum_{j in row} h16[j].
// Phase 1: TWO rows jointly per iteration, fully straight-line, all state in
// NAMED variables (R7 lesson: runtime-indexed local arrays -> scratch -> HBM
// spill disaster). 8 colv loads then 8 independent uint4 gathers issue
// back-to-back; packed-fp16 masked FMA reduce; rare wave-uniform tails.
// __launch_bounds__(256,6): VGPR cap ~85 gives room for 8 gathers in flight.
// Phase 2: [64 x IN_W] fp32 @ [IN_W x OUT_W], W from global (L1-resident).

template <int IN_W, int OUT_W, bool RELU, bool HAS_ADD, bool HAS_BIAS, bool W32, bool W16>
__global__ __launch_bounds__(256, 6) void gcn_kernel(
    const __half* __restrict__ h16, const float* __restrict__ Wg,
    const float* __restrict__ bias, const float* __restrict__ addsrc,
    const int* __restrict__ row_ptr, const int* __restrict__ colv,
    const float* __restrict__ dis,
    float* __restrict__ out32, __half* __restrict__ out16) {
    constexpr int TILE_R = 64;
    constexpr int QUADS = IN_W / 8;      // lanes per row (16B = 8 halves each)
    constexpr int SLOTS = 64 / QUADS;    // rows gathered per wave instruction
    constexpr int STR = IN_W + 4;
    __shared__ __align__(16) float aggT[TILE_R][STR];
    __shared__ int rp[TILE_R + 1];
    __shared__ float rdis[TILE_R];

    const int tid = threadIdx.x;
    const int tile0 = blockIdx.x * TILE_R;

    if (tid <= TILE_R) rp[tid] = row_ptr[min(tile0 + tid, NN)];
    if (tid < TILE_R) {
        const int i = tile0 + tid;
        rdis[tid] = (i < NN) ? dis[i] : 0.f;
    }
    __syncthreads();

    const int wave = tid >> 6;
    const int lane = tid & 63;
    const int fq = lane & (QUADS - 1);
    const int slot = lane / QUADS;
    const int rbase = wave << 4;
    const size_t fqo = (size_t)(fq << 3);

    const __half2 ONE2 = __float2half2_rn(1.0f);
    const __half2 ZERO2 = __float2half2_rn(0.0f);

    for (int hr = 0; hr < 8; ++hr) {
        const int rA = rbase + 2 * hr;
        const int rB = rA + 1;
        const int sA = __builtin_amdgcn_readfirstlane(rp[rA]);
        const int eA = __builtin_amdgcn_readfirstlane(rp[rA + 1]);
        const int sB = eA;
        const int eB = __builtin_amdgcn_readfirstlane(rp[rB + 1]);
        const int lastA = eA - 1, lastB = eB - 1;
        const int pA = sA + slot, pB = sB + slot;

        // 8 colv loads (independent)
        const int jA0 = colv[min(pA, lastA)];
        const int jA1 = colv[min(pA + SLOTS, lastA)];
        const int jA2 = colv[min(pA + 2 * SLOTS, lastA)];
        const int jA3 = colv[min(pA + 3 * SLOTS, lastA)];
        const int jB0 = colv[min(pB, lastB)];
        const int jB1 = colv[min(pB + SLOTS, lastB)];
        const int jB2 = colv[min(pB + 2 * SLOTS, lastB)];
        const int jB3 = colv[min(pB + 3 * SLOTS, lastB)];
        // 8 independent gathers
        const uint4 gA0 = *(const uint4*)(h16 + (size_t)jA0 * IN_W + fqo);
        const uint4 gA1 = *(const uint4*)(h16 + (size_t)jA1 * IN_W + fqo);
        const uint4 gA2 = *(const uint4*)(h16 + (size_t)jA2 * IN_W + fqo);
        const uint4 gA3 = *(const uint4*)(h16 + (size_t)jA3 * IN_W + fqo);
        const uint4 gB0 = *(const uint4*)(h16 + (size_t)jB0 * IN_W + fqo);
        const uint4 gB1 = *(const uint4*)(h16 + (size_t)jB1 * IN_W + fqo);
        const uint4 gB2 = *(const uint4*)(h16 + (size_t)jB2 * IN_W + fqo);
        const uint4 gB3 = *(const uint4*)(h16 + (size_t)jB3 * IN_W + fqo);

        __half2 aA[4] = {ZERO2, ZERO2, ZERO2, ZERO2};
        __half2 aB[4] = {ZERO2, ZERO2, ZERO2, ZERO2};
        {
            H2x4 hh;
            const __half2 mA0 = (pA < eA) ? ONE2 : ZERO2;
            const __half2 mA1 = (pA + SLOTS < eA) ? ONE2 : ZERO2;
            const __half2 mA2 = (pA + 2 * SLOTS < eA) ? ONE2 : ZERO2;
            const __half2 mA3 = (pA + 3 * SLOTS < eA) ? ONE2 : ZERO2;
            const __half2 mB0 = (pB < eB) ? ONE2 : ZERO2;
            const __half2 mB1 = (pB + SLOTS < eB) ? ONE2 : ZERO2;
            const __half2 mB2 = (pB + 2 * SLOTS < eB) ? ONE2 : ZERO2;
            const __half2 mB3 = (pB + 3 * SLOTS < eB) ? ONE2 : ZERO2;
            hh.u = gA0;
#pragma unroll
            for (int t = 0; t < 4; ++t) aA[t] = __hfma2(hh.h[t], mA0, aA[t]);
            hh.u = gA1;
#pragma unroll
            for (int t = 0; t < 4; ++t) aA[t] = __hfma2(hh.h[t], mA1, aA[t]);
            hh.u = gA2;
#pragma unroll
            for (int t = 0; t < 4; ++t) aA[t] = __hfma2(hh.h[t], mA2, aA[t]);
            hh.u = gA3;
#pragma unroll
            for (int t = 0; t < 4; ++t) aA[t] = __hfma2(hh.h[t], mA3, aA[t]);
            hh.u = gB0;
#pragma unroll
            for (int t = 0; t < 4; ++t) aB[t] = __hfma2(hh.h[t], mB0, aB[t]);
            hh.u = gB1;
#pragma unroll
            for (int t = 0; t < 4; ++t) aB[t] = __hfma2(hh.h[t], mB1, aB[t]);
            hh.u = gB2;
#pragma unroll
            for (int t = 0; t < 4; ++t) aB[t] = __hfma2(hh.h[t], mB2, aB[t]);
            hh.u = gB3;
#pragma unroll
            for (int t = 0; t < 4; ++t) aB[t] = __hfma2(hh.h[t], mB3, aB[t]);
        }
        // rare tails (deg > 4*SLOTS): wave-uniform branches
        if (eA - sA > 4 * SLOTS) {
            H2x4 hh;
            for (int p = pA + 4 * SLOTS; p < eA; p += SLOTS) {
                hh.u = *(const uint4*)(h16 + (size_t)colv[p] * IN_W + fqo);
#pragma unroll
                for (int t = 0; t < 4; ++t) aA[t] = __hadd2(aA[t], hh.h[t]);
            }
        }
        if (eB - sB > 4 * SLOTS) {
            H2x4 hh;
            for (int p = pB + 4 * SLOTS; p < eB; p += SLOTS) {
                hh.u = *(const uint4*)(h16 + (size_t)colv[p] * IN_W + fqo);
#pragma unroll
                for (int t = 0; t < 4; ++t) aB[t] = __hadd2(aB[t], hh.h[t]);
            }
        }
        // tree round 1 (fp16, xor = QUADS), both rows interleaved
#pragma unroll
        for (int t = 0; t < 4; ++t) {
            int vA = __shfl_xor(*reinterpret_cast<const int*>(&aA[t]), QUADS, 64);
            int vB = __shfl_xor(*reinterpret_cast<const int*>(&aB[t]), QUADS, 64);
            aA[t] = __hadd2(aA[t], *reinterpret_cast<const __half2*>(&vA));
            aB[t] = __hadd2(aB[t], *reinterpret_cast<const __half2*>(&vB));
        }
        float fA[8], fB[8];
#pragma unroll
        for (int t = 0; t < 4; ++t) {
            const float2 qA = __half22float2(aA[t]);
            const float2 qB = __half22float2(aB[t]);
            fA[2 * t] = qA.x; fA[2 * t + 1] = qA.y;
            fB[2 * t] = qB.x; fB[2 * t + 1] = qB.y;
        }
#pragma unroll
        for (int m = 2 * QUADS; m < 64; m <<= 1) {
#pragma unroll
            for (int t = 0; t < 8; ++t) fA[t] += __shfl_xor(fA[t], m, 64);
#pragma unroll
            for (int t = 0; t < 8; ++t) fB[t] += __shfl_xor(fB[t], m, 64);
        }
        if (slot == 0) {
            const float dA = rdis[rA], dB = rdis[rB];
#pragma unroll
            for (int t = 0; t < 8; ++t) { fA[t] *= dA; fB[t] *= dB; }
            *(float4*)&aggT[rA][(fq << 3)]     = make_float4(fA[0], fA[1], fA[2], fA[3]);
            *(float4*)&aggT[rA][(fq << 3) + 4] = make_float4(fA[4], fA[5], fA[6], fA[7]);
            *(float4*)&aggT[rB][(fq << 3)]     = make_float4(fB[0], fB[1], fB[2], fB[3]);
            *(float4*)&aggT[rB][(fq << 3) + 4] = make_float4(fB[4], fB[5], fB[6], fB[7]);
        }
    }
    __syncthreads();

    // phase 2: [64 x IN_W] fp32 @ [IN_W x OUT_W], W from global (L1-resident)
    constexpr int CPT = (OUT_W >= 4) ? 4 : OUT_W;
    constexpr int TXN = OUT_W / CPT;
    const int tx = tid % TXN;
    const int ty = tid / TXN;
    if (ty < TILE_R / 4) {
        float c[4][CPT];
#pragma unroll
        for (int r = 0; r < 4; ++r)
#pragma unroll
            for (int q = 0; q < CPT; ++q) c[r][q] = 0.f;

#pragma unroll 2
        for (int k4 = 0; k4 < IN_W / 4; ++k4) {
            float4 av[4];
#pragma unroll
            for (int r = 0; r < 4; ++r) av[r] = *(const float4*)&aggT[ty * 4 + r][k4 << 2];
#pragma unroll
            for (int kk = 0; kk < 4; ++kk) {
                float wv[CPT];
                if constexpr (CPT == 4) {
                    const float4 w4 = *(const float4*)(Wg + ((k4 << 2) + kk) * OUT_W + (tx << 2));
                    wv[0] = w4.x; wv[1] = w4.y; wv[2] = w4.z; wv[3] = w4.w;
                } else {
#pragma unroll
                    for (int q = 0; q < CPT; ++q)
                        wv[q] = Wg[((k4 << 2) + kk) * OUT_W + tx * CPT + q];
                }
#pragma unroll
                for (int r = 0; r < 4; ++r) {
                    const float ar = ((const float*)&av[r])[kk];
#pragma unroll
                    for (int q = 0; q < CPT; ++q) c[r][q] += ar * wv[q];
                }
            }
        }
        float bq[CPT];
#pragma unroll
        for (int q = 0; q < CPT; ++q) bq[q] = HAS_BIAS ? bias[tx * CPT + q] : 0.f;
#pragma unroll
        for (int r = 0; r < 4; ++r) {
            const int i = tile0 + ty * 4 + r;
            if (i < NN) {
                float o[CPT];
#pragma unroll
                for (int q = 0; q < CPT; ++q) o[q] = c[r][q] + bq[q];
                if constexpr (HAS_ADD) {
#pragma unroll
                    for (int q = 0; q < CPT; ++q) o[q] += addsrc[i * OUT_W + tx * CPT + q];
                }
                if constexpr (RELU) {
#pragma unroll
                    for (int q = 0; q < CPT; ++q) o[q] = fmaxf(o[q], 0.f);
                }
                if constexpr (W32) {
                    if constexpr (CPT == 4) {
                        *(float4*)(out32 + i * OUT_W + (tx << 2)) =
                            make_float4(o[0], o[1], o[2], o[3]);
                    } else {
#pragma unroll
                        for (int q = 0; q < CPT; ++q) out32[i * OUT_W + tx * CPT + q] = o[q];
                    }
                }
                if constexpr (W16) {
                    const float d = dis[i];
                    if constexpr (CPT == 4) {
                        union { uint2 u; __half2 h[2]; } pk;
                        pk.h[0] = __float22half2_rn(make_float2(o[0] * d, o[1] * d));
                        pk.h[1] = __float22half2_rn(make_float2(o[2] * d, o[3] * d));
                        *(uint2*)(out16 + i * OUT_W + (tx << 2)) = pk.u;
                    } else {
#pragma unroll
                        for (int q = 0; q < CPT; ++q)
                            out16[i * OUT_W + tx * CPT + q] = __float2half(o[q] * d);
                    }
                }
            }
        }
    }
}

// ---------------- driver ----------------

extern "C" void kernel_launch(void* const* d_in, const int* in_sizes, int n_in,
                              void* d_out, int out_size, void* d_ws, size_t ws_size,
                              hipStream_t stream) {
    const float* x   = (const float*)d_in[0];
    const float* Wp  = (const float*)d_in[1];
    const float* bp  = (const float*)d_in[2];
    const float* Wr  = (const float*)d_in[3];
    const float* br  = (const float*)d_in[4];
    const float* W11 = (const float*)d_in[5];
    const float* b11 = (const float*)d_in[6];
    const float* W12 = (const float*)d_in[7];
    const float* b12 = (const float*)d_in[8];
    const float* W21 = (const float*)d_in[9];
    const float* b21 = (const float*)d_in[10];
    const float* W22 = (const float*)d_in[11];
    const float* b22 = (const float*)d_in[12];
    const float* Wh1 = (const float*)d_in[13];
    const float* bh1 = (const float*)d_in[14];
    const float* Wh2 = (const float*)d_in[15];
    const float* bh2 = (const float*)d_in[16];
    const float* Wh3 = (const float*)d_in[17];
    const float* bh3 = (const float*)d_in[18];
    const int* edge  = (const int*)d_in[19];
    const int* srcA = edge;
    const int* dstA = edge + NE;
    float* outp = (float*)d_out;

    char* p = (char*)d_ws;
    auto carve = [&](size_t bytes) {
        char* r = p;
        p += (bytes + 255) & ~(size_t)255;
        return r;
    };
    int*    cnt  = (int*)carve(NN * 4);
    int*    fil  = (int*)carve(NN * 4);
    int*    rptr = (int*)carve((NN + 1) * 4);
    float*  dis  = (float*)carve(NN * 4);
    int*    sums = (int*)carve(128 * 4);
    int*    colv = (int*)carve((size_t)(NE + NN + 256) * 4);
    float4* xs4  = (float4*)carve((size_t)NN * 16);
    float*  ax   = (float*)carve((size_t)NN * 3 * 4);
    float*  xr   = (float*)carve((size_t)NN * 64 * 4);
    float*  bu32 = (float*)carve((size_t)NN * 64 * 4);
    float*  bw32 = (float*)carve((size_t)NN * 64 * 4);
    __half* bt16 = (__half*)carve((size_t)NN * 64 * 2);
    __half* bu16 = (__half*)carve((size_t)NN * 64 * 2);
    __half* bv16 = (__half*)carve((size_t)NN * 64 * 2);
    __half* bw16 = (__half*)carve((size_t)NN * 64 * 2);

    hipMemsetAsync(cnt, 0, NN * 4, stream);
    hipMemsetAsync(fil, 0, NN * 4, stream);
    count_kernel<<<(NE + 255) / 256, 256, 0, stream>>>(dstA, cnt);
    dis_xs_kernel<<<(NN + 255) / 256, 256, 0, stream>>>(cnt, x, dis, xs4);
    scan1_kernel<<<NCHUNK, 256, 0, stream>>>(cnt, rptr, sums);
    scan2_kernel<<<1, 128, 0, stream>>>(sums, rptr);
    scan3_kernel<<<(NN + 255) / 256, 256, 0, stream>>>(rptr, sums);
    fill_kernel<<<(NE + 255) / 256, 256, 0, stream>>>(srcA, dstA, rptr, fil, colv);
    selffill_kernel<<<(NN + 255) / 256, 256, 0, stream>>>(rptr, cnt, colv);
    aggx_kernel<<<(NN + 255) / 256, 256, 0, stream>>>(xs4, rptr, colv, dis, ax);
    proj_kernel<<<(NN * 64 + 255) / 256, 256, 0, stream>>>(ax, Wp, bp, Wr, br, dis, bt16, xr);

    const int GB = (NN + 63) / 64;
    for (int it = 0; it < 5; ++it) {
        gcn_kernel<64, 64, false, true, false, true, true><<<GB, 256, 0, stream>>>(
            bt16, Wr, nullptr, xr, rptr, colv, dis, bu32, bu16);
        gcn_kernel<64, 64, true, false, true, false, true><<<GB, 256, 0, stream>>>(
            bu16, W11, b11, nullptr, rptr, colv, dis, nullptr, bv16);
        gcn_kernel<64, 64, true, true, true, true, true><<<GB, 256, 0, stream>>>(
            bv16, W12, b12, bu32, rptr, colv, dis, bw32, bw16);
        gcn_kernel<64, 64, true, false, true, false, true><<<GB, 256, 0, stream>>>(
            bw16, W21, b21, nullptr, rptr, colv, dis, nullptr, bv16);
        gcn_kernel<64, 64, true, true, true, false, true><<<GB, 256, 0, stream>>>(
            bv16, W22, b22, bw32, rptr, colv, dis, nullptr, bt16);
    }
    gcn_kernel<64, 32, true, false, true, false, true><<<GB, 256, 0, stream>>>(
        bt16, Wh1, bh1, nullptr, rptr, colv, dis, nullptr, bv16);
    gcn_kernel<32, 8, true, false, true, false, true><<<GB, 256, 0, stream>>>(
        bv16, Wh2, bh2, nullptr, rptr, colv, dis, nullptr, bw16);
    gcn_kernel<8, 2, false, false, true, true, false><<<GB, 256, 0, stream>>>(
        bw16, Wh3, bh3, nullptr, rptr, colv, dis, outp, nullptr);
}

// Round 9
// 1579.951 us; speedup vs baseline: 3.6037x; 1.0628x over previous
//
#include <hip/hip_runtime.h>
#include <hip/hip_fp16.h>

#define NN 100000
#define NE 1600000
#define CHUNK 1024
#define NCHUNK ((NN + CHUNK - 1) / CHUNK)
#define NBUCK 196            // dst >> 9  (512 nodes per bucket)
#define BCAP 9216            // mean 8192, sigma ~90 -> +11 sigma
#define PA_EDGES 4096

union H2x4 { uint4 u; __half2 h[4]; };

// ---------------- CSR build: two-pass LDS radix binning ----------------

// Pass A: bin edges into NBUCK dst-buckets. Per block: LDS count -> scan ->
// place (bucket-sorted stage) -> reserve global space -> coalesced flush.
__global__ __launch_bounds__(256) void binA_kernel(const int* __restrict__ src,
                                                   const int* __restrict__ dst,
                                                   int* __restrict__ gcnt,
                                                   unsigned* __restrict__ bins) {
    __shared__ int lcnt[256], lofs[256], lfil[256], gbase[256];
    __shared__ unsigned stage[PA_EDGES];
    const int tid = threadIdx.x;
    const int e0 = blockIdx.x * PA_EDGES;
    lcnt[tid] = 0; lfil[tid] = 0;
    __syncthreads();
    // count
    for (int k = 0; k < PA_EDGES / 256; ++k) {
        const int e = e0 + k * 256 + tid;
        if (e < NE) atomicAdd(&lcnt[dst[e] >> 9], 1);
    }
    __syncthreads();
    // exclusive scan of lcnt
    const int v = lcnt[tid];
    lofs[tid] = v;
    __syncthreads();
    for (int off = 1; off < 256; off <<= 1) {
        int xv = (tid >= off) ? lofs[tid - off] : 0;
        __syncthreads();
        lofs[tid] += xv;
        __syncthreads();
    }
    const int excl = lofs[tid] - v;
    __syncthreads();
    lofs[tid] = excl;
    // reserve global segment per bucket
    if (tid < NBUCK && v > 0) gbase[tid] = atomicAdd(&gcnt[tid], v);
    else gbase[tid] = 0;
    __syncthreads();
    // place into bucket-sorted LDS stage (word = src<<9 | dst&511)
    for (int k = 0; k < PA_EDGES / 256; ++k) {
        const int e = e0 + k * 256 + tid;
        if (e < NE) {
            const int d = dst[e];
            const int b = d >> 9;
            const int p = atomicAdd(&lfil[b], 1);
            stage[lofs[b] + p] = ((unsigned)src[e] << 9) | (unsigned)(d & 511);
        }
    }
    __syncthreads();
    // coalesced flush: wave w handles buckets w, w+4, ...
    const int wave = tid >> 6, lane = tid & 63;
    for (int b = wave; b < NBUCK; b += 4) {
        const int n = lcnt[b];
        const int base = gbase[b];
        const int off = lofs[b];
        for (int k = lane; k < n; k += 64) {
            const int gpos = base + k;
            if (gpos < BCAP) bins[(size_t)b * BCAP + gpos] = stage[off + k];
        }
    }
}

// Pass B1: per-bucket node histogram -> cnt (coalesced write; replaces count)
__global__ __launch_bounds__(256) void binB1_kernel(const unsigned* __restrict__ bins,
                                                    const int* __restrict__ gcnt,
                                                    int* __restrict__ cnt) {
    __shared__ int c512[512];
    const int b = blockIdx.x, tid = threadIdx.x;
    c512[tid] = 0; c512[256 + tid] = 0;
    __syncthreads();
    const int n = min(gcnt[b], BCAP);
    for (int k = tid; k < n; k += 256)
        atomicAdd(&c512[bins[(size_t)b * BCAP + k] & 511], 1);
    __syncthreads();
    const int i0 = b * 512 + tid;
    const int i1 = i0 + 256;
    if (i0 < NN) cnt[i0] = c512[tid];
    if (i1 < NN) cnt[i1] = c512[256 + tid];
}

// Pass B2: bucket-local scatter into col (writes land in a ~35KB L2 window)
__global__ __launch_bounds__(256) void binB2_kernel(const unsigned* __restrict__ bins,
                                                    const int* __restrict__ gcnt,
                                                    const int* __restrict__ rptr,
                                                    int* __restrict__ col) {
    __shared__ int fil512[512];
    __shared__ int rp_l[512];
    const int b = blockIdx.x, tid = threadIdx.x;
    fil512[tid] = 0; fil512[256 + tid] = 0;
    const int i0 = b * 512 + tid;
    const int i1 = i0 + 256;
    rp_l[tid]       = (i0 < NN) ? rptr[i0] : 0;
    rp_l[256 + tid] = (i1 < NN) ? rptr[i1] : 0;
    __syncthreads();
    const int n = min(gcnt[b], BCAP);
    for (int k = tid; k < n; k += 256) {
        const unsigned w = bins[(size_t)b * BCAP + k];
        const int dl = (int)(w & 511);
        const int s = (int)(w >> 9);
        const int p = atomicAdd(&fil512[dl], 1);
        col[rp_l[dl] + p] = s;
    }
}

// dis[i] = rsqrt(deg_i+1);  xs4 = dis-prescaled x rows, padded to float4
__global__ void dis_xs_kernel(const int* __restrict__ cnt, const float* __restrict__ x,
                              float* __restrict__ dis, float4* __restrict__ xs4) {
    int i = blockIdx.x * blockDim.x + threadIdx.x;
    if (i >= NN) return;
    float d = rsqrtf((float)(cnt[i] + 1));
    dis[i] = d;
    xs4[i] = make_float4(d * x[i * 3 + 0], d * x[i * 3 + 1], d * x[i * 3 + 2], 0.f);
}

// hierarchical exclusive scan of (cnt[i]+1)  [self-loop included in CSR]
__global__ __launch_bounds__(256) void scan1_kernel(const int* __restrict__ cnt,
                                                    int* __restrict__ row_ptr,
                                                    int* __restrict__ sums) {
    __shared__ int sdata[256];
    const int b = blockIdx.x, t = threadIdx.x;
    const int base = b * CHUNK + t * 4;
    int v0 = (base + 0 < NN) ? cnt[base + 0] + 1 : 0;
    int v1 = (base + 1 < NN) ? cnt[base + 1] + 1 : 0;
    int v2 = (base + 2 < NN) ? cnt[base + 2] + 1 : 0;
    int v3 = (base + 3 < NN) ? cnt[base + 3] + 1 : 0;
    const int s = v0 + v1 + v2 + v3;
    sdata[t] = s;
    __syncthreads();
    for (int off = 1; off < 256; off <<= 1) {
        int xv = (t >= off) ? sdata[t - off] : 0;
        __syncthreads();
        sdata[t] += xv;
        __syncthreads();
    }
    const int excl = sdata[t] - s;
    if (base + 0 < NN) row_ptr[base + 0] = excl;
    if (base + 1 < NN) row_ptr[base + 1] = excl + v0;
    if (base + 2 < NN) row_ptr[base + 2] = excl + v0 + v1;
    if (base + 3 < NN) row_ptr[base + 3] = excl + v0 + v1 + v2;
    if (t == 255) sums[b] = sdata[255];
}

__global__ __launch_bounds__(128) void scan2_kernel(int* __restrict__ sums,
                                                    int* __restrict__ row_ptr) {
    __shared__ int sd[128];
    const int t = threadIdx.x;
    const int v = (t < NCHUNK) ? sums[t] : 0;
    sd[t] = v;
    __syncthreads();
    for (int off = 1; off < 128; off <<= 1) {
        int xv = (t >= off) ? sd[t - off] : 0;
        __syncthreads();
        sd[t] += xv;
        __syncthreads();
    }
    if (t < NCHUNK) sums[t] = sd[t] - v;
    if (t == 127) row_ptr[NN] = sd[127];
}

__global__ void scan3_kernel(int* __restrict__ row_ptr, const int* __restrict__ sums) {
    int i = blockIdx.x * blockDim.x + threadIdx.x;
    if (i < NN) row_ptr[i] += sums[i >> 10];
}

__global__ void selffill_kernel(const int* __restrict__ row_ptr, const int* __restrict__ cnt,
                                int* __restrict__ col) {
    int i = blockIdx.x * blockDim.x + threadIdx.x;
    if (i >= NN) return;
    col[row_ptr[i] + cnt[i]] = i;  // self edge last in the row
}

// ax = Ahat @ x = dis_i * sum_j xs[j]   (CSR includes self loop)
__global__ void aggx_kernel(const float4* __restrict__ xs4, const int* __restrict__ row_ptr,
                            const int* __restrict__ col, const float* __restrict__ dis,
                            float* __restrict__ ax) {
    int i = blockIdx.x * blockDim.x + threadIdx.x;
    if (i >= NN) return;
    float a0 = 0.f, a1 = 0.f, a2 = 0.f;
    const int s = row_ptr[i], e = row_ptr[i + 1];
    int p = s;
    for (; p + 2 <= e; p += 2) {
        const float4 v0 = xs4[col[p]];
        const float4 v1 = xs4[col[p + 1]];
        a0 += v0.x + v1.x; a1 += v0.y + v1.y; a2 += v0.z + v1.z;
    }
    if (p < e) {
        const float4 v = xs4[col[p]];
        a0 += v.x; a1 += v.y; a2 += v.z;
    }
    const float d = dis[i];
    ax[i * 3 + 0] = d * a0; ax[i * 3 + 1] = d * a1; ax[i * 3 + 2] = d * a2;
}

// t16 = fp16(dis * relu(ax @ Wp + bp));  xr = ax @ Wr[64:67,:] + br
__global__ void proj_kernel(const float* __restrict__ ax,
                            const float* __restrict__ Wp, const float* __restrict__ bp,
                            const float* __restrict__ Wr, const float* __restrict__ br,
                            const float* __restrict__ dis,
                            __half* __restrict__ t16, float* __restrict__ xr) {
    int g = blockIdx.x * blockDim.x + threadIdx.x;
    if (g >= NN * 64) return;
    int i = g >> 6, c = g & 63;
    float a0 = ax[i * 3 + 0], a1 = ax[i * 3 + 1], a2 = ax[i * 3 + 2];
    float tp = fmaxf(a0 * Wp[c] + a1 * Wp[64 + c] + a2 * Wp[128 + c] + bp[c], 0.f);
    t16[g] = __float2half(tp * dis[i]);
    xr[g] = a0 * Wr[64 * 64 + c] + a1 * Wr[65 * 64 + c] + a2 * Wr[66 * 64 + c] + br[c];
}

// ---------------- fused GCN ----------------
// h16 rows fp16, pre-scaled by dis[j]. agg_i = dis_i * sum_{j in row} h16[j].
// Phase 1: two rows jointly, straight-line, named vars only (R7 lesson).
// __launch_bounds__(256,4): 1563 blocks / 1024 resident = 1.5 generations so
// phase 2 (barrier-serialized VALU+LDS) of finished blocks overlaps phase 1
// (fabric-bound gathers) of later blocks; VGPR cap 128 gives scheduler slack.
// Phase 2: [64 x IN_W] fp32 @ [IN_W x OUT_W], W from global (L1-resident).

template <int IN_W, int OUT_W, bool RELU, bool HAS_ADD, bool HAS_BIAS, bool W32, bool W16>
__global__ __launch_bounds__(256, 4) void gcn_kernel(
    const __half* __restrict__ h16, const float* __restrict__ Wg,
    const float* __restrict__ bias, const float* __restrict__ addsrc,
    const int* __restrict__ row_ptr, const int* __restrict__ colv,
    const float* __restrict__ dis,
    float* __restrict__ out32, __half* __restrict__ out16) {
    constexpr int TILE_R = 64;
    constexpr int QUADS = IN_W / 8;      // lanes per row (16B = 8 halves each)
    constexpr int SLOTS = 64 / QUADS;    // rows gathered per wave instruction
    constexpr int STR = IN_W + 4;
    __shared__ __align__(16) float aggT[TILE_R][STR];
    __shared__ int rp[TILE_R + 1];
    __shared__ float rdis[TILE_R];

    const int tid = threadIdx.x;
    const int tile0 = blockIdx.x * TILE_R;

    if (tid <= TILE_R) rp[tid] = row_ptr[min(tile0 + tid, NN)];
    if (tid < TILE_R) {
        const int i = tile0 + tid;
        rdis[tid] = (i < NN) ? dis[i] : 0.f;
    }
    __syncthreads();

    const int wave = tid >> 6;
    const int lane = tid & 63;
    const int fq = lane & (QUADS - 1);
    const int slot = lane / QUADS;
    const int rbase = wave << 4;
    const size_t fqo = (size_t)(fq << 3);

    const __half2 ONE2 = __float2half2_rn(1.0f);
    const __half2 ZERO2 = __float2half2_rn(0.0f);

    for (int hr = 0; hr < 8; ++hr) {
        const int rA = rbase + 2 * hr;
        const int rB = rA + 1;
        const int sA = __builtin_amdgcn_readfirstlane(rp[rA]);
        const int eA = __builtin_amdgcn_readfirstlane(rp[rA + 1]);
        const int sB = eA;
        const int eB = __builtin_amdgcn_readfirstlane(rp[rB + 1]);
        const int lastA = eA - 1, lastB = eB - 1;
        const int pA = sA + slot, pB = sB + slot;

        // 8 colv loads (independent)
        const int jA0 = colv[min(pA, lastA)];
        const int jA1 = colv[min(pA + SLOTS, lastA)];
        const int jA2 = colv[min(pA + 2 * SLOTS, lastA)];
        const int jA3 = colv[min(pA + 3 * SLOTS, lastA)];
        const int jB0 = colv[min(pB, lastB)];
        const int jB1 = colv[min(pB + SLOTS, lastB)];
        const int jB2 = colv[min(pB + 2 * SLOTS, lastB)];
        const int jB3 = colv[min(pB + 3 * SLOTS, lastB)];
        // 8 independent gathers
        const uint4 gA0 = *(const uint4*)(h16 + (size_t)jA0 * IN_W + fqo);
        const uint4 gA1 = *(const uint4*)(h16 + (size_t)jA1 * IN_W + fqo);
        const uint4 gA2 = *(const uint4*)(h16 + (size_t)jA2 * IN_W + fqo);
        const uint4 gA3 = *(const uint4*)(h16 + (size_t)jA3 * IN_W + fqo);
        const uint4 gB0 = *(const uint4*)(h16 + (size_t)jB0 * IN_W + fqo);
        const uint4 gB1 = *(const uint4*)(h16 + (size_t)jB1 * IN_W + fqo);
        const uint4 gB2 = *(const uint4*)(h16 + (size_t)jB2 * IN_W + fqo);
        const uint4 gB3 = *(const uint4*)(h16 + (size_t)jB3 * IN_W + fqo);

        __half2 aA[4] = {ZERO2, ZERO2, ZERO2, ZERO2};
        __half2 aB[4] = {ZERO2, ZERO2, ZERO2, ZERO2};
        {
            H2x4 hh;
            const __half2 mA0 = (pA < eA) ? ONE2 : ZERO2;
            const __half2 mA1 = (pA + SLOTS < eA) ? ONE2 : ZERO2;
            const __half2 mA2 = (pA + 2 * SLOTS < eA) ? ONE2 : ZERO2;
            const __half2 mA3 = (pA + 3 * SLOTS < eA) ? ONE2 : ZERO2;
            const __half2 mB0 = (pB < eB) ? ONE2 : ZERO2;
            const __half2 mB1 = (pB + SLOTS < eB) ? ONE2 : ZERO2;
            const __half2 mB2 = (pB + 2 * SLOTS < eB) ? ONE2 : ZERO2;
            const __half2 mB3 = (pB + 3 * SLOTS < eB) ? ONE2 : ZERO2;
            hh.u = gA0;
#pragma unroll
            for (int t = 0; t < 4; ++t) aA[t] = __hfma2(hh.h[t], mA0, aA[t]);
            hh.u = gA1;
#pragma unroll
            for (int t = 0; t < 4; ++t) aA[t] = __hfma2(hh.h[t], mA1, aA[t]);
            hh.u = gA2;
#pragma unroll
            for (int t = 0; t < 4; ++t) aA[t] = __hfma2(hh.h[t], mA2, aA[t]);
            hh.u = gA3;
#pragma unroll
            for (int t = 0; t < 4; ++t) aA[t] = __hfma2(hh.h[t], mA3, aA[t]);
            hh.u = gB0;
#pragma unroll
            for (int t = 0; t < 4; ++t) aB[t] = __hfma2(hh.h[t], mB0, aB[t]);
            hh.u = gB1;
#pragma unroll
            for (int t = 0; t < 4; ++t) aB[t] = __hfma2(hh.h[t], mB1, aB[t]);
            hh.u = gB2;
#pragma unroll
            for (int t = 0; t < 4; ++t) aB[t] = __hfma2(hh.h[t], mB2, aB[t]);
            hh.u = gB3;
#pragma unroll
            for (int t = 0; t < 4; ++t) aB[t] = __hfma2(hh.h[t], mB3, aB[t]);
        }
        // rare tails (deg > 4*SLOTS): wave-uniform branches
        if (eA - sA > 4 * SLOTS) {
            H2x4 hh;
            for (int p = pA + 4 * SLOTS; p < eA; p += SLOTS) {
                hh.u = *(const uint4*)(h16 + (size_t)colv[p] * IN_W + fqo);
#pragma unroll
                for (int t = 0; t < 4; ++t) aA[t] = __hadd2(aA[t], hh.h[t]);
            }
        }
        if (eB - sB > 4 * SLOTS) {
            H2x4 hh;
            for (int p = pB + 4 * SLOTS; p < eB; p += SLOTS) {
                hh.u = *(const uint4*)(h16 + (size_t)colv[p] * IN_W + fqo);
#pragma unroll
                for (int t = 0; t < 4; ++t) aB[t] = __hadd2(aB[t], hh.h[t]);
            }
        }
        // tree round 1 (fp16, xor = QUADS), both rows interleaved
#pragma unroll
        for (int t = 0; t < 4; ++t) {
            int vA = __shfl_xor(*reinterpret_cast<const int*>(&aA[t]), QUADS, 64);
            int vB = __shfl_xor(*reinterpret_cast<const int*>(&aB[t]), QUADS, 64);
            aA[t] = __hadd2(aA[t], *reinterpret_cast<const __half2*>(&vA));
            aB[t] = __hadd2(aB[t], *reinterpret_cast<const __half2*>(&vB));
        }
        float fA[8], fB[8];
#pragma unroll
        for (int t = 0; t < 4; ++t) {
            const float2 qA = __half22float2(aA[t]);
            const float2 qB = __half22float2(aB[t]);
            fA[2 * t] = qA.x; fA[2 * t + 1] = qA.y;
            fB[2 * t] = qB.x; fB[2 * t + 1] = qB.y;
        }
#pragma unroll
        for (int m = 2 * QUADS; m < 64; m <<= 1) {
#pragma unroll
            for (int t = 0; t < 8; ++t) fA[t] += __shfl_xor(fA[t], m, 64);
#pragma unroll
            for (int t = 0; t < 8; ++t) fB[t] += __shfl_xor(fB[t], m, 64);
        }
        if (slot == 0) {
            const float dA = rdis[rA], dB = rdis[rB];
#pragma unroll
            for (int t = 0; t < 8; ++t) { fA[t] *= dA; fB[t] *= dB; }
            *(float4*)&aggT[rA][(fq << 3)]     = make_float4(fA[0], fA[1], fA[2], fA[3]);
            *(float4*)&aggT[rA][(fq << 3) + 4] = make_float4(fA[4], fA[5], fA[6], fA[7]);
            *(float4*)&aggT[rB][(fq << 3)]     = make_float4(fB[0], fB[1], fB[2], fB[3]);
            *(float4*)&aggT[rB][(fq << 3) + 4] = make_float4(fB[4], fB[5], fB[6], fB[7]);
        }
    }
    __syncthreads();

    // phase 2: [64 x IN_W] fp32 @ [IN_W x OUT_W], W from global (L1-resident)
    constexpr int CPT = (OUT_W >= 4) ? 4 : OUT_W;
    constexpr int TXN = OUT_W / CPT;
    const int tx = tid % TXN;
    const int ty = tid / TXN;
    if (ty < TILE_R / 4) {
        float c[4][CPT];
#pragma unroll
        for (int r = 0; r < 4; ++r)
#pragma unroll
            for (int q = 0; q < CPT; ++q) c[r][q] = 0.f;

#pragma unroll 2
        for (int k4 = 0; k4 < IN_W / 4; ++k4) {
            float4 av[4];
#pragma unroll
            for (int r = 0; r < 4; ++r) av[r] = *(const float4*)&aggT[ty * 4 + r][k4 << 2];
#pragma unroll
            for (int kk = 0; kk < 4; ++kk) {
                float wv[CPT];
                if constexpr (CPT == 4) {
                    const float4 w4 = *(const float4*)(Wg + ((k4 << 2) + kk) * OUT_W + (tx << 2));
                    wv[0] = w4.x; wv[1] = w4.y; wv[2] = w4.z; wv[3] = w4.w;
                } else {
#pragma unroll
                    for (int q = 0; q < CPT; ++q)
                        wv[q] = Wg[((k4 << 2) + kk) * OUT_W + tx * CPT + q];
                }
#pragma unroll
                for (int r = 0; r < 4; ++r) {
                    const float ar = ((const float*)&av[r])[kk];
#pragma unroll
                    for (int q = 0; q < CPT; ++q) c[r][q] += ar * wv[q];
                }
            }
        }
        float bq[CPT];
#pragma unroll
        for (int q = 0; q < CPT; ++q) bq[q] = HAS_BIAS ? bias[tx * CPT + q] : 0.f;
#pragma unroll
        for (int r = 0; r < 4; ++r) {
            const int i = tile0 + ty * 4 + r;
            if (i < NN) {
                float o[CPT];
#pragma unroll
                for (int q = 0; q < CPT; ++q) o[q] = c[r][q] + bq[q];
                if constexpr (HAS_ADD) {
#pragma unroll
                    for (int q = 0; q < CPT; ++q) o[q] += addsrc[i * OUT_W + tx * CPT + q];
                }
                if constexpr (RELU) {
#pragma unroll
                    for (int q = 0; q < CPT; ++q) o[q] = fmaxf(o[q], 0.f);
                }
                if constexpr (W32) {
                    if constexpr (CPT == 4) {
                        *(float4*)(out32 + i * OUT_W + (tx << 2)) =
                            make_float4(o[0], o[1], o[2], o[3]);
                    } else {
#pragma unroll
                        for (int q = 0; q < CPT; ++q) out32[i * OUT_W + tx * CPT + q] = o[q];
                    }
                }
                if constexpr (W16) {
                    const float d = dis[i];
                    if constexpr (CPT == 4) {
                        union { uint2 u; __half2 h[2]; } pk;
                        pk.h[0] = __float22half2_rn(make_float2(o[0] * d, o[1] * d));
                        pk.h[1] = __float22half2_rn(make_float2(o[2] * d, o[3] * d));
                        *(uint2*)(out16 + i * OUT_W + (tx << 2)) = pk.u;
                    } else {
#pragma unroll
                        for (int q = 0; q < CPT; ++q)
                            out16[i * OUT_W + tx * CPT + q] = __float2half(o[q] * d);
                    }
                }
            }
        }
    }
}

// ---------------- driver ----------------

extern "C" void kernel_launch(void* const* d_in, const int* in_sizes, int n_in,
                              void* d_out, int out_size, void* d_ws, size_t ws_size,
                              hipStream_t stream) {
    const float* x   = (const float*)d_in[0];
    const float* Wp  = (const float*)d_in[1];
    const float* bp  = (const float*)d_in[2];
    const float* Wr  = (const float*)d_in[3];
    const float* br  = (const float*)d_in[4];
    const float* W11 = (const float*)d_in[5];
    const float* b11 = (const float*)d_in[6];
    const float* W12 = (const float*)d_in[7];
    const float* b12 = (const float*)d_in[8];
    const float* W21 = (const float*)d_in[9];
    const float* b21 = (const float*)d_in[10];
    const float* W22 = (const float*)d_in[11];
    const float* b22 = (const float*)d_in[12];
    const float* Wh1 = (const float*)d_in[13];
    const float* bh1 = (const float*)d_in[14];
    const float* Wh2 = (const float*)d_in[15];
    const float* bh2 = (const float*)d_in[16];
    const float* Wh3 = (const float*)d_in[17];
    const float* bh3 = (const float*)d_in[18];
    const int* edge  = (const int*)d_in[19];
    const int* srcA = edge;
    const int* dstA = edge + NE;
    float* outp = (float*)d_out;

    char* p = (char*)d_ws;
    auto carve = [&](size_t bytes) {
        char* r = p;
        p += (bytes + 255) & ~(size_t)255;
        return r;
    };
    int*      cnt   = (int*)carve(NN * 4);
    int*      rptr  = (int*)carve((NN + 1) * 4);
    float*    dis   = (float*)carve(NN * 4);
    int*      sums  = (int*)carve(128 * 4);
    int*      gcnt  = (int*)carve(256 * 4);
    unsigned* bins  = (unsigned*)carve((size_t)NBUCK * BCAP * 4);
    int*      colv  = (int*)carve((size_t)(NE + NN + 256) * 4);
    float4*   xs4   = (float4*)carve((size_t)NN * 16);
    float*    ax    = (float*)carve((size_t)NN * 3 * 4);
    float*    xr    = (float*)carve((size_t)NN * 64 * 4);
    float*    bu32  = (float*)carve((size_t)NN * 64 * 4);
    float*    bw32  = (float*)carve((size_t)NN * 64 * 4);
    __half*   bt16  = (__half*)carve((size_t)NN * 64 * 2);
    __half*   bu16  = (__half*)carve((size_t)NN * 64 * 2);
    __half*   bv16  = (__half*)carve((size_t)NN * 64 * 2);
    __half*   bw16  = (__half*)carve((size_t)NN * 64 * 2);

    hipMemsetAsync(gcnt, 0, 256 * 4, stream);
    const int GA = (NE + PA_EDGES - 1) / PA_EDGES;
    binA_kernel<<<GA, 256, 0, stream>>>(srcA, dstA, gcnt, bins);
    binB1_kernel<<<NBUCK, 256, 0, stream>>>(bins, gcnt, cnt);
    dis_xs_kernel<<<(NN + 255) / 256, 256, 0, stream>>>(cnt, x, dis, xs4);
    scan1_kernel<<<NCHUNK, 256, 0, stream>>>(cnt, rptr, sums);
    scan2_kernel<<<1, 128, 0, stream>>>(sums, rptr);
    scan3_kernel<<<(NN + 255) / 256, 256, 0, stream>>>(rptr, sums);
    binB2_kernel<<<NBUCK, 256, 0, stream>>>(bins, gcnt, rptr, colv);
    selffill_kernel<<<(NN + 255) / 256, 256, 0, stream>>>(rptr, cnt, colv);
    aggx_kernel<<<(NN + 255) / 256, 256, 0, stream>>>(xs4, rptr, colv, dis, ax);
    proj_kernel<<<(NN * 64 + 255) / 256, 256, 0, stream>>>(ax, Wp, bp, Wr, br, dis, bt16, xr);

    const int GB = (NN + 63) / 64;
    for (int it = 0; it < 5; ++it) {
        gcn_kernel<64, 64, false, true, false, true, true><<<GB, 256, 0, stream>>>(
            bt16, Wr, nullptr, xr, rptr, colv, dis, bu32, bu16);
        gcn_kernel<64, 64, true, false, true, false, true><<<GB, 256, 0, stream>>>(
            bu16, W11, b11, nullptr, rptr, colv, dis, nullptr, bv16);
        gcn_kernel<64, 64, true, true, true, true, true><<<GB, 256, 0, stream>>>(
            bv16, W12, b12, bu32, rptr, colv, dis, bw32, bw16);
        gcn_kernel<64, 64, true, false, true, false, true><<<GB, 256, 0, stream>>>(
            bw16, W21, b21, nullptr, rptr, colv, dis, nullptr, bv16);
        gcn_kernel<64, 64, true, true, true, false, true><<<GB, 256, 0, stream>>>(
            bv16, W22, b22, bw32, rptr, colv, dis, nullptr, bt16);
    }
    gcn_kernel<64, 32, true, false, true, false, true><<<GB, 256, 0, stream>>>(
        bt16, Wh1, bh1, nullptr, rptr, colv, dis, nullptr, bv16);
    gcn_kernel<32, 8, true, false, true, false, true><<<GB, 256, 0, stream>>>(
        bv16, Wh2, bh2, nullptr, rptr, colv, dis, nullptr, bw16);
    gcn_kernel<8, 2, false, false, true, true, false><<<GB, 256, 0, stream>>>(
        bw16, Wh3, bh3, nullptr, rptr, colv, dis, outp, nullptr);
}